// Round 3
// baseline (1812.976 us; speedup 1.0000x reference)
//
#include <hip/hip_runtime.h>
#include <hip/hip_fp16.h>

#define N    1024
#define BSZ  32
#define PS   480     // per-sample param stride: 169 W13 + 147 w1 + 147 w2 + 9 kA
#define HID  100

// ---------------------------------------------------------------------------
// Kernel 1: per-sample MLPs + composed 13x13 kernel (unchanged)
// ---------------------------------------------------------------------------
__global__ __launch_bounds__(256) void prep_kernel(
    const float* __restrict__ kernelA,
    const float* __restrict__ fc1_w1, const float* __restrict__ fc1_b1,
    const float* __restrict__ fc1_w2, const float* __restrict__ fc1_b2,
    const float* __restrict__ fc2_w1, const float* __restrict__ fc2_b1,
    const float* __restrict__ fc2_w2, const float* __restrict__ fc2_b2,
    float* __restrict__ params)
{
    int b = blockIdx.x, t = threadIdx.x;
    __shared__ float w[9], h1[HID], h2[HID], w1[147], w2[147];
    if (t < 9) w[t] = kernelA[b * 9 + t];
    __syncthreads();
    if (t < HID) {
        float s1 = fc1_b1[t], s2 = fc2_b1[t];
        #pragma unroll
        for (int i = 0; i < 9; ++i) {
            s1 = fmaf(w[i], fc1_w1[i * HID + t], s1);
            s2 = fmaf(w[i], fc2_w1[i * HID + t], s2);
        }
        h1[t] = fmaxf(s1, 0.f);
        h2[t] = fmaxf(s2, 0.f);
    }
    __syncthreads();
    if (t < 147) {
        float s1 = fc1_b2[t], s2 = fc2_b2[t];
        for (int i = 0; i < HID; ++i) {
            s1 = fmaf(h1[i], fc1_w2[i * 147 + t], s1);
            s2 = fmaf(h2[i], fc2_w2[i * 147 + t], s2);
        }
        w1[t] = s1;
        w2[t] = s2;
    }
    __syncthreads();
    float* P = params + b * PS;
    if (t < 169) {   // W13[ey][ex] = sum_m sum_{d1+d2=e} w1[m,d1] * w2[m,d2]
        int ey = t / 13, ex = t % 13;
        float s = 0.f;
        for (int m = 0; m < 3; ++m)
            for (int d1y = 0; d1y < 7; ++d1y) {
                int d2y = ey - d1y;
                if (d2y < 0 || d2y > 6) continue;
                for (int d1x = 0; d1x < 7; ++d1x) {
                    int d2x = ex - d1x;
                    if (d2x < 0 || d2x > 6) continue;
                    s = fmaf(w1[m * 49 + d1y * 7 + d1x],
                             w2[m * 49 + d2y * 7 + d2x], s);
                }
            }
        P[t] = s;
    }
    if (t < 147) { P[169 + t] = w1[t]; P[316 + t] = w2[t]; }
    if (t < 9)   P[463 + t] = w[t];
}

// ---------------------------------------------------------------------------
// Kernel 2: interior 13x13 composed conv.
// r stored as FP16 in LDS: 44 x 152 halves = 13.4 KB -> 8 blocks/CU (max
// 32 waves/CU). fp16 r adds ~0.02 abs error to G2 (budget 0.5).
//   phase A: r = f - corr3x3(x,kA) straight from global, packed to half2,
//            quad written to LDS as b64. ONE __syncthreads.
//   phase B: 2 rows x 8 cols per thread. Window row = 20 halves = 40 B =
//            uint4 + uint4 + uint2 (3 LDS instrs, 16B-aligned). 16 window-row
//            reads/thread (vs 88 b128 in fp32 version): LDS bytes and instr
//            count both ~halved. Three SMEM-segregated tap passes (taps in
//            SGPRs, pure-DS inner loops) with winA/winB double buffer.
//            fp16->fp32 via fpext folded into v_fma_mix where matched.
// ---------------------------------------------------------------------------
#define TR  32
#define TC  128
#define RRW 44      // r rows = TR + 12
#define RC_H 152    // r row pitch in halves (>=140, mult of 8 -> 16B rows)
#define QPR 35      // float4-quads per r row (140 data halves)
#define NQ  (RRW * QPR)   // 1540

struct WinH { uint4 a, b; uint2 c; };   // 20 halves, contiguous 40 B

__device__ __forceinline__ float hval(const unsigned int* u, int h) {
    const __half2 p = *reinterpret_cast<const __half2*>(u + (h >> 1));
    return (h & 1) ? __high2float(p) : __low2float(p);
}

// declare one 13-tap kernel row as named scalars (uniform -> SGPRs)
#define DECL_ROW(R, base)                                                     \
    const float R##_0 = P[(base)],      R##_1 = P[(base) + 1],                \
                R##_2 = P[(base) + 2],  R##_3 = P[(base) + 3],                \
                R##_4 = P[(base) + 4],  R##_5 = P[(base) + 5],                \
                R##_6 = P[(base) + 6],  R##_7 = P[(base) + 7],                \
                R##_8 = P[(base) + 8],  R##_9 = P[(base) + 9],                \
                R##_10 = P[(base) + 10], R##_11 = P[(base) + 11],             \
                R##_12 = P[(base) + 12];

// one tap column c applied to 8 outputs
#define CR8C(u, R, a, c)                                                      \
    (a)[0] = fmaf(hval(u, (c) + 0), R##_##c, (a)[0]);                         \
    (a)[1] = fmaf(hval(u, (c) + 1), R##_##c, (a)[1]);                         \
    (a)[2] = fmaf(hval(u, (c) + 2), R##_##c, (a)[2]);                         \
    (a)[3] = fmaf(hval(u, (c) + 3), R##_##c, (a)[3]);                         \
    (a)[4] = fmaf(hval(u, (c) + 4), R##_##c, (a)[4]);                         \
    (a)[5] = fmaf(hval(u, (c) + 5), R##_##c, (a)[5]);                         \
    (a)[6] = fmaf(hval(u, (c) + 6), R##_##c, (a)[6]);                         \
    (a)[7] = fmaf(hval(u, (c) + 7), R##_##c, (a)[7]);

// one 13-tap kernel row applied to an 8-wide output slice
#define CR8(w, R, a) do {                                                     \
    const unsigned int* _u = reinterpret_cast<const unsigned int*>(&(w));     \
    CR8C(_u, R, a, 0)  CR8C(_u, R, a, 1)  CR8C(_u, R, a, 2)                   \
    CR8C(_u, R, a, 3)  CR8C(_u, R, a, 4)  CR8C(_u, R, a, 5)                   \
    CR8C(_u, R, a, 6)  CR8C(_u, R, a, 7)  CR8C(_u, R, a, 8)                   \
    CR8C(_u, R, a, 9)  CR8C(_u, R, a, 10) CR8C(_u, R, a, 11)                  \
    CR8C(_u, R, a, 12) } while (0)

#define LWH(w, rr) {                                                          \
    const __half* _p = &rbuf_h[(trow + (rr)) * RC_H + tcol];                  \
    (w).a = *reinterpret_cast<const uint4*>(_p);                              \
    (w).b = *reinterpret_cast<const uint4*>(_p + 8);                          \
    (w).c = *reinterpret_cast<const uint2*>(_p + 16); }

__global__ __launch_bounds__(256, 8) void main_kernel(
    const float* __restrict__ X, const float* __restrict__ F,
    const float* __restrict__ params, float* __restrict__ out)
{
    __shared__ __align__(16) __half rbuf_h[RRW * RC_H];   // 13376 B
    const int t  = threadIdx.x;
    const int b  = blockIdx.z;
    const int y0 = blockIdx.y * TR;
    const int x0 = blockIdx.x * TC;
    const float* P  = params + b * PS;
    const float* Xb = X + (size_t)b * N * N;
    const float* Fb = F + (size_t)b * N * N;
    float*       Ob = out + (size_t)b * N * N;

    float ka[9];
    #pragma unroll
    for (int i = 0; i < 9; ++i) ka[i] = P[463 + i];  // uniform -> SGPR

    // ---- phase A: r tile straight from global into LDS (as half), quads.
    // r origin = (y0-6, x0-6); quad col start gc == 2 (mod 4), so the 8-wide
    // x window [gc-2, gc+5] is two 16B-aligned float4 and f is two aligned
    // float2. Boundary crossings land on vector boundaries.
    for (int idx = t; idx < NQ; idx += 256) {
        int i  = idx / QPR;
        int j  = (idx - i * QPR) * 4;
        int gr = y0 - 6 + i;          // global r row
        int gc = x0 - 6 + j;          // global col of quad start
        float4 v = make_float4(0.f, 0.f, 0.f, 0.f);
        if (gr >= 0 && gr < N) {
            float w8[3][8];
            #pragma unroll
            for (int dy = 0; dy < 3; ++dy) {
                int ry = gr - 1 + dy;
                float4 qa = make_float4(0.f, 0.f, 0.f, 0.f);
                float4 qb = make_float4(0.f, 0.f, 0.f, 0.f);
                if (ry >= 0 && ry < N) {
                    const float* xr = Xb + (size_t)ry * N;
                    if (gc - 2 >= 0 && gc + 1 < N)
                        qa = *reinterpret_cast<const float4*>(xr + gc - 2);
                    if (gc + 2 >= 0 && gc + 5 < N)
                        qb = *reinterpret_cast<const float4*>(xr + gc + 2);
                }
                w8[dy][0] = qa.x; w8[dy][1] = qa.y; w8[dy][2] = qa.z; w8[dy][3] = qa.w;
                w8[dy][4] = qb.x; w8[dy][5] = qb.y; w8[dy][6] = qb.z; w8[dy][7] = qb.w;
            }
            float s[4] = {0.f, 0.f, 0.f, 0.f};
            #pragma unroll
            for (int dy = 0; dy < 3; ++dy)
                #pragma unroll
                for (int dx = 0; dx < 3; ++dx) {
                    float kv = ka[dy * 3 + dx];
                    #pragma unroll
                    for (int c = 0; c < 4; ++c)
                        s[c] = fmaf(kv, w8[dy][c + dx + 1], s[c]);
                }
            const float* fr = Fb + (size_t)gr * N;
            if (gc >= 0 && gc + 1 < N) {
                float2 f0 = *reinterpret_cast<const float2*>(fr + gc);
                v.x = f0.x - s[0]; v.y = f0.y - s[1];
            }
            if (gc + 2 >= 0 && gc + 3 < N) {
                float2 f1 = *reinterpret_cast<const float2*>(fr + gc + 2);
                v.z = f1.x - s[2]; v.w = f1.y - s[3];
            }
        }
        __half2 p0, p1;
        p0.x = __float2half_rn(v.x); p0.y = __float2half_rn(v.y);
        p1.x = __float2half_rn(v.z); p1.y = __float2half_rn(v.w);
        uint2 st;
        st.x = *reinterpret_cast<unsigned int*>(&p0);
        st.y = *reinterpret_cast<unsigned int*>(&p1);
        *reinterpret_cast<uint2*>(&rbuf_h[i * RC_H + j]) = st;   // b64, 8B-aligned
    }
    __syncthreads();

    // ---- phase B: 2 rows x 8 cols per thread, 3 SMEM-segregated tap passes
    const int tcol = (t & 15) * 8;   // col offset 0..120 (16B lane stride)
    const int trow = (t >> 4) * 2;   // row offset 0..30

    float acc0[8] = {0.f,0.f,0.f,0.f,0.f,0.f,0.f,0.f};
    float acc1[8] = {0.f,0.f,0.f,0.f,0.f,0.f,0.f,0.f};
    WinH wA, wB;

    // pass 0: tap rows ky 0..4, window rows 0..5
    {
        DECL_ROW(K0, 0)  DECL_ROW(K1, 13) DECL_ROW(K2, 26)
        DECL_ROW(K3, 39) DECL_ROW(K4, 52)
        LWH(wA, 0) LWH(wB, 1)
        CR8(wA, K0, acc0);
        LWH(wA, 2)
        CR8(wB, K1, acc0); CR8(wB, K0, acc1);
        LWH(wB, 3)
        CR8(wA, K2, acc0); CR8(wA, K1, acc1);
        LWH(wA, 4)
        CR8(wB, K3, acc0); CR8(wB, K2, acc1);
        LWH(wB, 5)
        CR8(wA, K4, acc0); CR8(wA, K3, acc1);
        CR8(wB, K4, acc1);
    }
    // pass 1: tap rows ky 5..9, window rows 5..10
    {
        DECL_ROW(K5, 65)  DECL_ROW(K6, 78) DECL_ROW(K7, 91)
        DECL_ROW(K8, 104) DECL_ROW(K9, 117)
        LWH(wA, 5) LWH(wB, 6)
        CR8(wA, K5, acc0);
        LWH(wA, 7)
        CR8(wB, K6, acc0); CR8(wB, K5, acc1);
        LWH(wB, 8)
        CR8(wA, K7, acc0); CR8(wA, K6, acc1);
        LWH(wA, 9)
        CR8(wB, K8, acc0); CR8(wB, K7, acc1);
        LWH(wB, 10)
        CR8(wA, K9, acc0); CR8(wA, K8, acc1);
        CR8(wB, K9, acc1);
    }
    // pass 2: tap rows ky 10..12, window rows 10..13
    {
        DECL_ROW(K10, 130) DECL_ROW(K11, 143) DECL_ROW(K12, 156)
        LWH(wA, 10) LWH(wB, 11)
        CR8(wA, K10, acc0);
        LWH(wA, 12)
        CR8(wB, K11, acc0); CR8(wB, K10, acc1);
        LWH(wB, 13)
        CR8(wA, K12, acc0); CR8(wA, K11, acc1);
        CR8(wB, K12, acc1);
    }

    // ---- epilogue: out = x + G2 (x re-read from global, coalesced b128)
    #pragma unroll
    for (int i = 0; i < 2; ++i) {
        const int gy = y0 + trow + i;
        const float* ac = (i == 0) ? acc0 : acc1;
        const float4 x0q = *reinterpret_cast<const float4*>(
            &Xb[(size_t)gy * N + x0 + tcol]);
        const float4 x1q = *reinterpret_cast<const float4*>(
            &Xb[(size_t)gy * N + x0 + tcol + 4]);
        float4 o0, o1;
        o0.x = x0q.x + ac[0]; o0.y = x0q.y + ac[1];
        o0.z = x0q.z + ac[2]; o0.w = x0q.w + ac[3];
        o1.x = x1q.x + ac[4]; o1.y = x1q.y + ac[5];
        o1.z = x1q.z + ac[6]; o1.w = x1q.w + ac[7];
        *reinterpret_cast<float4*>(&Ob[(size_t)gy * N + x0 + tcol])     = o0;
        *reinterpret_cast<float4*>(&Ob[(size_t)gy * N + x0 + tcol + 4]) = o1;
    }
}

// ---------------------------------------------------------------------------
// Kernel 3: exact two-stage recompute of the width-3 border band (unchanged)
// ---------------------------------------------------------------------------
#define SEG 64
#define AXX 14          // x across size
#define AXU (SEG + 14)  // x along size   78
#define ARR 12          // r across size
#define ARU (SEG + 12)  // r along size   76
#define ATA 6           // tmp across size
#define ATU (SEG + 6)   // tmp along size 70

__global__ __launch_bounds__(256) void border_kernel(
    const float* __restrict__ X, const float* __restrict__ F,
    const float* __restrict__ params, float* __restrict__ out)
{
    __shared__ float xs[AXX * AXU];
    __shared__ float rs[ARR * ARU];
    __shared__ float tmp[3 * ATA * ATU];
    __shared__ float sw1[147], sw2[147];

    const int  t    = threadIdx.x;
    const int  b    = blockIdx.y;
    const int  seg  = blockIdx.x;
    const int  edge = seg >> 4;          // 0 top, 1 bottom, 2 left, 3 right
    const int  s    = seg & 15;
    const bool vert = edge >= 2;
    const bool hi   = (edge == 1) || (edge == 3);
    const int  T0   = hi ? (N - 6) : 0;  // tmp across origin
    const int  V0   = hi ? (N - 3) : 0;  // output across origin
    const int  D    = hi ? 3 : 0;        // V0 - T0
    const int  u0   = vert ? (3 + s * SEG) : (s * SEG);
    const int  acr0x = T0 - 4, al0x = u0 - 7;
    const int  acr0r = T0 - 3, al0r = u0 - 6;

    const float* P  = params + b * PS;
    const float* Xb = X + (size_t)b * N * N;
    const float* Fb = F + (size_t)b * N * N;
    float*       Ob = out + (size_t)b * N * N;

    if (t < 147) { sw1[t] = P[169 + t]; sw2[t] = P[316 + t]; }
    float ka[9];
    #pragma unroll
    for (int i = 0; i < 9; ++i) ka[i] = P[463 + i];

    // stage x (zero-extended)
    for (int idx = t; idx < AXX * AXU; idx += 256) {
        int a = vert ? (idx % AXX) : (idx / AXU);
        int u = vert ? (idx / AXX) : (idx % AXU);
        int ga = acr0x + a, gl = al0x + u;
        int gy = vert ? gl : ga, gx = vert ? ga : gl;
        xs[a * AXU + u] =
            (gy >= 0 && gy < N && gx >= 0 && gx < N) ? Xb[gy * N + gx] : 0.f;
    }
    __syncthreads();

    // r = f - corr3x3(x,kA), zero outside image
    for (int idx = t; idx < ARR * ARU; idx += 256) {
        int a = vert ? (idx % ARR) : (idx / ARU);
        int u = vert ? (idx / ARR) : (idx % ARU);
        int ga = acr0r + a, gl = al0r + u;
        int gy = vert ? gl : ga, gx = vert ? ga : gl;
        float v = 0.f;
        if (gy >= 0 && gy < N && gx >= 0 && gx < N) {
            float sc = 0.f;
            #pragma unroll
            for (int da = 0; da < 3; ++da)
                #pragma unroll
                for (int dl = 0; dl < 3; ++dl)
                    sc = fmaf(ka[vert ? (dl * 3 + da) : (da * 3 + dl)],
                              xs[(a + da) * AXU + (u + dl)], sc);
            v = Fb[gy * N + gx] - sc;
        }
        rs[a * ARU + u] = v;
    }
    __syncthreads();

    // tmp[m, a, u]: zero if along position outside image (reference zeroing)
    for (int idx = t; idx < 3 * ATA * ATU; idx += 256) {
        int m   = idx / (ATA * ATU);
        int rem = idx - m * (ATA * ATU);
        int a = rem / ATU, u = rem % ATU;
        int gl = (u0 - 3) + u;
        float sc = 0.f;
        if (gl >= 0 && gl < N) {
            #pragma unroll
            for (int da = 0; da < 7; ++da)
                #pragma unroll
                for (int dl = 0; dl < 7; ++dl)
                    sc = fmaf(sw1[m * 49 + (vert ? (dl * 7 + da) : (da * 7 + dl))],
                              rs[(a + da) * ARU + (u + dl)], sc);
        }
        tmp[idx] = sc;
    }
    __syncthreads();

    // outputs: 3 across x SEG along
    for (int idx = t; idx < 3 * SEG; idx += 256) {
        int v = idx / SEG, u = idx - (idx / SEG) * SEG;
        int gl = u0 + u, ga = V0 + v;
        if (vert && gl >= N - 3) continue;   // partial last vertical segment
        float sc = 0.f;
        #pragma unroll
        for (int m = 0; m < 3; ++m)
            #pragma unroll
            for (int d2a = 0; d2a < 7; ++d2a) {
                int aT = v + d2a - 3 + D;    // tmp across index; OOR => ref zeroes
                if (aT < 0 || aT >= ATA) continue;
                #pragma unroll
                for (int d2l = 0; d2l < 7; ++d2l)
                    sc = fmaf(sw2[m * 49 + (vert ? (d2l * 7 + d2a) : (d2a * 7 + d2l))],
                              tmp[(m * ATA + aT) * ATU + (u + d2l)], sc);
            }
        int gy = vert ? gl : ga, gx = vert ? ga : gl;
        float xv = xs[(ga - acr0x) * AXU + (gl - al0x)];
        Ob[gy * N + gx] = xv + sc;
    }
}

// ---------------------------------------------------------------------------
extern "C" void kernel_launch(void* const* d_in, const int* in_sizes, int n_in,
                              void* d_out, int out_size, void* d_ws, size_t ws_size,
                              hipStream_t stream)
{
    const float* x    = (const float*)d_in[0];
    const float* f    = (const float*)d_in[1];
    const float* kA   = (const float*)d_in[2];
    const float* f1w1 = (const float*)d_in[3];
    const float* f1b1 = (const float*)d_in[4];
    const float* f1w2 = (const float*)d_in[5];
    const float* f1b2 = (const float*)d_in[6];
    const float* f2w1 = (const float*)d_in[7];
    const float* f2b1 = (const float*)d_in[8];
    const float* f2w2 = (const float*)d_in[9];
    const float* f2b2 = (const float*)d_in[10];
    float* out    = (float*)d_out;
    float* params = (float*)d_ws;   // BSZ * PS floats = 61440 B

    prep_kernel<<<BSZ, 256, 0, stream>>>(kA, f1w1, f1b1, f1w2, f1b2,
                                         f2w1, f2b1, f2w2, f2b2, params);
    main_kernel<<<dim3(N / TC, N / TR, BSZ), 256, 0, stream>>>(x, f, params, out);
    border_kernel<<<dim3(64, BSZ), 256, 0, stream>>>(x, f, params, out);
}